// Round 8
// baseline (4036.895 us; speedup 1.0000x reference)
//
#include <hip/hip_runtime.h>
#include <math.h>

#define N_NODES 100000
#define N_EDGES 1600000
#define IN_DIM 128
#define HEADS 8
#define D1 16
#define D2 8
#define NEG_SLOPE 0.2f

// ---------------------------------------------------------------------------
// Software-pipelined GEMM: C[n_rows, OUTC] = A[n_rows, K] @ W[K, OUTC].
// 4x4 tile per thread, explicit ping-pong prefetch (load c4+1 while
// computing c4). R7 post-mortem: the 8x8 tile at 84 VGPR couldn't keep any
// loads in flight across iterations (per-iter state 64 regs) and the 782-
// block grid was a single occupancy batch -> 144 us at VALUBusy 16%.
// Here: in-flight state 64 regs + 16 acc fits under the 128-VGPR cap from
// __launch_bounds__(256,4), grid is 3125/1563 blocks, and each wave hides
// ~200-cyc L2 W-load latency behind 128 cyc of FMA.
// ---------------------------------------------------------------------------
template<int K, int OUTC>
__global__ __launch_bounds__(256, 4)
void gemm_tile4_kernel(const float* __restrict__ A, const float* __restrict__ W,
                       float* __restrict__ C, int n_rows) {
    constexpr int CT = OUTC / 4;       // col-threads per row group (32 or 16)
    constexpr int RT = 256 / CT;       // row-threads (8 or 16)
    constexpr int BM = RT * 4;         // rows per block (32 or 64)
    int tid = threadIdx.x;
    int ct = tid % CT;
    int rt = tid / CT;
    int row0 = blockIdx.x * BM + rt * 4;
    int col0 = ct * 4;

    const float* ap[4];
#pragma unroll
    for (int r = 0; r < 4; ++r) {
        int rr = row0 + r;
        rr = rr < n_rows ? rr : n_rows - 1;   // clamp: keep address valid
        ap[r] = A + (long)rr * K;
    }
    const float* wp = W + col0;

    float4 acc[4];
#pragma unroll
    for (int r = 0; r < 4; ++r) acc[r] = make_float4(0.f, 0.f, 0.f, 0.f);

    auto loadA = [&](float4* dst, int c4) {
#pragma unroll
        for (int r = 0; r < 4; ++r) dst[r] = *(const float4*)(ap[r] + c4 * 4);
    };
    auto loadW = [&](float4* dst, int c4) {
#pragma unroll
        for (int k = 0; k < 4; ++k) dst[k] = *(const float4*)(wp + (c4 * 4 + k) * OUTC);
    };
    auto doFMA = [&](const float4* a, const float4* w) {
#pragma unroll
        for (int r = 0; r < 4; ++r) {
            acc[r].x = fmaf(a[r].x, w[0].x, acc[r].x);
            acc[r].y = fmaf(a[r].x, w[0].y, acc[r].y);
            acc[r].z = fmaf(a[r].x, w[0].z, acc[r].z);
            acc[r].w = fmaf(a[r].x, w[0].w, acc[r].w);
            acc[r].x = fmaf(a[r].y, w[1].x, acc[r].x);
            acc[r].y = fmaf(a[r].y, w[1].y, acc[r].y);
            acc[r].z = fmaf(a[r].y, w[1].z, acc[r].z);
            acc[r].w = fmaf(a[r].y, w[1].w, acc[r].w);
            acc[r].x = fmaf(a[r].z, w[2].x, acc[r].x);
            acc[r].y = fmaf(a[r].z, w[2].y, acc[r].y);
            acc[r].z = fmaf(a[r].z, w[2].z, acc[r].z);
            acc[r].w = fmaf(a[r].z, w[2].w, acc[r].w);
            acc[r].x = fmaf(a[r].w, w[3].x, acc[r].x);
            acc[r].y = fmaf(a[r].w, w[3].y, acc[r].y);
            acc[r].z = fmaf(a[r].w, w[3].z, acc[r].z);
            acc[r].w = fmaf(a[r].w, w[3].w, acc[r].w);
        }
    };

    float4 aP[4], wP[4], aQ[4], wQ[4];
    loadA(aP, 0); loadW(wP, 0);
#pragma unroll
    for (int c4 = 0; c4 < K / 4; c4 += 2) {
        // prefetch c4+1 while computing c4  (K/4 is even, c4+1 always valid)
        loadA(aQ, c4 + 1); loadW(wQ, c4 + 1);
        doFMA(aP, wP);
        if (c4 + 2 < K / 4) { loadA(aP, c4 + 2); loadW(wP, c4 + 2); }
        doFMA(aQ, wQ);
    }

#pragma unroll
    for (int r = 0; r < 4; ++r) {
        int rr = row0 + r;
        if (rr < n_rows) {
            *(float4*)(C + (long)rr * OUTC + col0) = acc[r];
        }
    }
}

// ---------------------------------------------------------------------------
// Attention scores: one thread per (node, head); float4 loads of the D-vec.
// ---------------------------------------------------------------------------
template<int D>
__global__ void scores_kernel(const float* __restrict__ h,
                              const float* __restrict__ a_src,
                              const float* __restrict__ a_dst,
                              float* __restrict__ s_src,
                              float* __restrict__ s_dst) {
    int i = blockIdx.x * blockDim.x + threadIdx.x;   // over N_NODES*HEADS
    if (i >= N_NODES * HEADS) return;
    int hd = i & 7;
    const float4* hp = (const float4*)(h + (long)i * D);
    const float4* as = (const float4*)(a_src + hd * D);
    const float4* ad = (const float4*)(a_dst + hd * D);
    float ss = 0.f, sd = 0.f;
#pragma unroll
    for (int r = 0; r < D / 4; ++r) {
        float4 v = hp[r], s4 = as[r], d4 = ad[r];
        ss = fmaf(v.x, s4.x, ss); ss = fmaf(v.y, s4.y, ss);
        ss = fmaf(v.z, s4.z, ss); ss = fmaf(v.w, s4.w, ss);
        sd = fmaf(v.x, d4.x, sd); sd = fmaf(v.y, d4.y, sd);
        sd = fmaf(v.z, d4.z, sd); sd = fmaf(v.w, d4.w, sd);
    }
    s_src[i] = ss;
    s_dst[i] = sd;
}

// ---------------------------------------------------------------------------
// CSR build: count -> block scan -> scan of block sums -> add offsets -> scatter
// ---------------------------------------------------------------------------
__global__ void count_kernel(const int* __restrict__ dst, int* __restrict__ counts) {
    int e = blockIdx.x * blockDim.x + threadIdx.x;
    if (e < N_EDGES) atomicAdd(&counts[dst[e]], 1);
}

__global__ void scan_block_kernel(const int* __restrict__ counts, int* __restrict__ rs,
                                  int* __restrict__ bsums, int n) {
    __shared__ int sh[256];
    int tid = threadIdx.x;
    int base = blockIdx.x * 1024 + tid * 4;
    int c0 = (base + 0 < n) ? counts[base + 0] : 0;
    int c1 = (base + 1 < n) ? counts[base + 1] : 0;
    int c2 = (base + 2 < n) ? counts[base + 2] : 0;
    int c3 = (base + 3 < n) ? counts[base + 3] : 0;
    int p1 = c0, p2 = c0 + c1, p3 = c0 + c1 + c2, tot = c0 + c1 + c2 + c3;
    sh[tid] = tot;
    __syncthreads();
    int run = tot;
    for (int off = 1; off < 256; off <<= 1) {
        int add = (tid >= off) ? sh[tid - off] : 0;
        __syncthreads();
        run += add;
        sh[tid] = run;
        __syncthreads();
    }
    int excl = run - tot;
    if (base + 0 < n) rs[base + 0] = excl;
    if (base + 1 < n) rs[base + 1] = excl + p1;
    if (base + 2 < n) rs[base + 2] = excl + p2;
    if (base + 3 < n) rs[base + 3] = excl + p3;
    if (tid == 255) bsums[blockIdx.x] = run;   // block total
}

__global__ void scan_sums_kernel(int* __restrict__ bsums, int nb) {
    if (blockIdx.x == 0 && threadIdx.x == 0) {
        int run = 0;
        for (int i = 0; i < nb; ++i) { int c = bsums[i]; bsums[i] = run; run += c; }
    }
}

__global__ void add_offsets_kernel(int* __restrict__ rs, const int* __restrict__ bsums,
                                   int* __restrict__ cursor, int n) {
    int tid = threadIdx.x;
    int base = blockIdx.x * 1024 + tid * 4;
    int add = bsums[blockIdx.x];
#pragma unroll
    for (int j = 0; j < 4; ++j) {
        int i = base + j;
        if (i < n) { int v = rs[i] + add; rs[i] = v; cursor[i] = v; }
    }
    if (blockIdx.x == 0 && tid == 0) rs[n] = N_EDGES;
}

__global__ void scatter_kernel(const int* __restrict__ src, const int* __restrict__ dst,
                               int* __restrict__ cursor, int* __restrict__ eidx) {
    int e = blockIdx.x * blockDim.x + threadIdx.x;
    if (e >= N_EDGES) return;
    int d = dst[e];
    int pos = atomicAdd(&cursor[d], 1);
    eidx[pos] = src[e];
}

// ---------------------------------------------------------------------------
// Wave-per-node fused aggregation + softmax + finalize (R7 structure).
// One wave = one dst node; 64 lanes span the feature row; per edge one
// coalesced row load; eidx wave-uniform; 4x unroll keeps 4 gathers in
// flight at ~12 VGPRs of state.
// ---------------------------------------------------------------------------
template<int D, bool RELU>
__global__ __launch_bounds__(256)
void aggregate_wave_kernel(const int* __restrict__ rs, const int* __restrict__ eidx,
                           const float* __restrict__ h,
                           const float* __restrict__ ssrc, const float* __restrict__ sdst,
                           const float* __restrict__ bias, float* __restrict__ out) {
    constexpr int F = HEADS * D;       // 128 or 64
    constexpr int EPL = F / 64;        // elements per lane: 2 or 1
    int lane = threadIdx.x & 63;
    int node = blockIdx.x * (256 / 64) + (threadIdx.x >> 6);
    node = __builtin_amdgcn_readfirstlane(node);
    if (node >= N_NODES) return;
    int hd = lane >> 3;                // head owning this lane's slice

    float sdv = sdst[node * HEADS + hd];
    // self-loop contribution
    float sc0 = ssrc[node * HEADS + hd] + sdv;
    float w0 = __expf(sc0 > 0.f ? sc0 : NEG_SLOPE * sc0);
    float wsum = w0;

    float accx, accy = 0.f;
    if constexpr (EPL == 2) {
        float2 v = *(const float2*)(h + (long)node * F + lane * 2);
        accx = w0 * v.x; accy = w0 * v.y;
    } else {
        accx = w0 * h[(long)node * F + lane];
    }

    int e0 = rs[node], e1 = rs[node + 1];
    int e = e0;

    // ---- unroll-by-4: independent addresses, ~12 VGPRs of in-flight state ----
    for (; e + 4 <= e1; e += 4) {
        int sA = eidx[e + 0];
        int sB = eidx[e + 1];
        int sC = eidx[e + 2];
        int sD = eidx[e + 3];
        float cA = ssrc[sA * HEADS + hd] + sdv;
        float cB = ssrc[sB * HEADS + hd] + sdv;
        float cC = ssrc[sC * HEADS + hd] + sdv;
        float cD = ssrc[sD * HEADS + hd] + sdv;
        float wA = __expf(cA > 0.f ? cA : NEG_SLOPE * cA);
        float wB = __expf(cB > 0.f ? cB : NEG_SLOPE * cB);
        float wC = __expf(cC > 0.f ? cC : NEG_SLOPE * cC);
        float wD = __expf(cD > 0.f ? cD : NEG_SLOPE * cD);
        wsum += (wA + wB) + (wC + wD);
        if constexpr (EPL == 2) {
            float2 vA = *(const float2*)(h + (long)sA * F + lane * 2);
            float2 vB = *(const float2*)(h + (long)sB * F + lane * 2);
            float2 vC = *(const float2*)(h + (long)sC * F + lane * 2);
            float2 vD = *(const float2*)(h + (long)sD * F + lane * 2);
            accx = fmaf(wA, vA.x, accx); accy = fmaf(wA, vA.y, accy);
            accx = fmaf(wB, vB.x, accx); accy = fmaf(wB, vB.y, accy);
            accx = fmaf(wC, vC.x, accx); accy = fmaf(wC, vC.y, accy);
            accx = fmaf(wD, vD.x, accx); accy = fmaf(wD, vD.y, accy);
        } else {
            float vA = h[(long)sA * F + lane];
            float vB = h[(long)sB * F + lane];
            float vC = h[(long)sC * F + lane];
            float vD = h[(long)sD * F + lane];
            accx = fmaf(wA, vA, accx);
            accx = fmaf(wB, vB, accx);
            accx = fmaf(wC, vC, accx);
            accx = fmaf(wD, vD, accx);
        }
    }

    // ---- remainder ----
    for (; e < e1; ++e) {
        int s = eidx[e];
        float sc = ssrc[s * HEADS + hd] + sdv;
        float we = __expf(sc > 0.f ? sc : NEG_SLOPE * sc);
        wsum += we;
        if constexpr (EPL == 2) {
            float2 v = *(const float2*)(h + (long)s * F + lane * 2);
            accx = fmaf(we, v.x, accx); accy = fmaf(we, v.y, accy);
        } else {
            accx = fmaf(we, h[(long)s * F + lane], accx);
        }
    }

    float inv = 1.f / (wsum + 1e-16f);
    if constexpr (EPL == 2) {
        float2 b = *(const float2*)(bias + lane * 2);
        float ox = accx * inv + b.x;
        float oy = accy * inv + b.y;
        if (RELU) { ox = fmaxf(ox, 0.f); oy = fmaxf(oy, 0.f); }
        *(float2*)(out + (long)node * F + lane * 2) = make_float2(ox, oy);
    } else {
        float o = accx * inv + bias[lane];
        if (RELU) o = fmaxf(o, 0.f);
        out[(long)node * F + lane] = o;
    }
}

extern "C" void kernel_launch(void* const* d_in, const int* in_sizes, int n_in,
                              void* d_out, int out_size, void* d_ws, size_t ws_size,
                              hipStream_t stream) {
    const float* x   = (const float*)d_in[0];
    const int*   ei  = (const int*)d_in[1];      // [2, N_EDGES] row-major
    const float* W1  = (const float*)d_in[2];
    const float* a1s = (const float*)d_in[3];
    const float* a1d = (const float*)d_in[4];
    const float* b1  = (const float*)d_in[5];
    const float* W2  = (const float*)d_in[6];
    const float* a2s = (const float*)d_in[7];
    const float* a2d = (const float*)d_in[8];
    const float* b2  = (const float*)d_in[9];
    float* out = (float*)d_out;

    const int* src = ei;
    const int* dst = ei + N_EDGES;

    // ---- workspace layout ----
    float* ws = (float*)d_ws;
    float* bufA = ws;                                  // N*128 : h1, later h2 (N*64)
    float* bufB = bufA + (size_t)N_NODES * 128;        // N*128 : out1
    float* ssrc = bufB + (size_t)N_NODES * 128;        // N*8
    float* sdst = ssrc + (size_t)N_NODES * HEADS;      // N*8
    int* counts    = (int*)(sdst + (size_t)N_NODES * HEADS);  // N
    int* row_start = counts + N_NODES;                 // N+1
    int* cursor    = row_start + N_NODES + 1;          // N
    int* bsums     = cursor + N_NODES;                 // 128
    int* eidx      = bsums + 128;                      // N_EDGES

    const int nb_scan = (N_NODES + 1023) / 1024;       // 98

    // ---- CSR build (shared by both layers) ----
    hipMemsetAsync(counts, 0, (size_t)N_NODES * sizeof(int), stream);
    count_kernel<<<(N_EDGES + 255) / 256, 256, 0, stream>>>(dst, counts);
    scan_block_kernel<<<nb_scan, 256, 0, stream>>>(counts, row_start, bsums, N_NODES);
    scan_sums_kernel<<<1, 64, 0, stream>>>(bsums, nb_scan);
    add_offsets_kernel<<<nb_scan, 256, 0, stream>>>(row_start, bsums, cursor, N_NODES);
    scatter_kernel<<<(N_EDGES + 255) / 256, 256, 0, stream>>>(src, dst, cursor, eidx);

    // ---- Layer 1 ----
    gemm_tile4_kernel<128, 128><<<(N_NODES + 31) / 32, 256, 0, stream>>>(x, W1, bufA, N_NODES);
    scores_kernel<D1><<<(N_NODES * HEADS + 255) / 256, 256, 0, stream>>>(bufA, a1s, a1d, ssrc, sdst);
    aggregate_wave_kernel<D1, true><<<(N_NODES + 3) / 4, 256, 0, stream>>>(
        row_start, eidx, bufA, ssrc, sdst, b1, bufB);

    // ---- Layer 2 ----
    gemm_tile4_kernel<128, 64><<<(N_NODES + 63) / 64, 256, 0, stream>>>(bufB, W2, bufA, N_NODES);
    scores_kernel<D2><<<(N_NODES * HEADS + 255) / 256, 256, 0, stream>>>(bufA, a2s, a2d, ssrc, sdst);
    aggregate_wave_kernel<D2, false><<<(N_NODES + 3) / 4, 256, 0, stream>>>(
        row_start, eidx, bufA, ssrc, sdst, b2, out);
}

// Round 9
// 3228.608 us; speedup vs baseline: 1.2504x; 1.2504x over previous
//
#include <hip/hip_runtime.h>
#include <math.h>

#define N_NODES 100000
#define N_EDGES 1600000
#define IN_DIM 128
#define HEADS 8
#define D1 16
#define D2 8
#define NEG_SLOPE 0.2f

// ---------------------------------------------------------------------------
// LDS-staged GEMM: C[n_rows, OUTC] = A[n_rows, K] @ W[K, OUTC].
// R7 diagnosis: W (64 KB) > L1 (32 KB) so inner-loop W loads were ~200-cyc
// L2 hits with too few waves to hide them (144 us, VALUBusy 16%).
// Fix: stage W into LDS in 64-k-row halves (32/16 KB); inner loop reads W
// via ds_read_b128 (~12 cyc). A rows get a 2-deep ping-pong prefetch.
// R8 lesson: NO lambdas / address-taken arrays — straight unrolled loops
// over plain locals so SROA promotes them to VGPRs (R8's lambda pointer
// params put everything in scratch: 2.5 GB spill traffic).
// Tile RPT x 8 per thread; acc = RPT*8 regs; VGPR ~110 -> 4 waves/SIMD.
// ---------------------------------------------------------------------------
template<int K, int OUTC, int RPT>
__global__ __launch_bounds__(256)
void gemm_lds_kernel(const float* __restrict__ A, const float* __restrict__ W,
                     float* __restrict__ C, int n_rows) {
    constexpr int CT = OUTC / 8;        // col-threads (16 or 8)
    constexpr int RT = 256 / CT;        // row-threads (16 or 32)
    constexpr int BM = RT * RPT;        // rows per block
    constexpr int KH = 64;              // k-rows staged per half
    __shared__ float wlds[KH * OUTC];   // 32 KB (OUTC=128) / 16 KB (OUTC=64)

    int tid = threadIdx.x;
    int ct = tid % CT;
    int rt = tid / CT;
    int row0 = blockIdx.x * BM + rt * RPT;
    int col0 = ct * 8;

    const float* ap[RPT];
#pragma unroll
    for (int r = 0; r < RPT; ++r) {
        int rr = row0 + r;
        rr = rr < n_rows ? rr : n_rows - 1;   // clamp: keep address valid
        ap[r] = A + (long)rr * K;
    }

    float4 acc[RPT][2];
#pragma unroll
    for (int r = 0; r < RPT; ++r) {
        acc[r][0] = make_float4(0.f, 0.f, 0.f, 0.f);
        acc[r][1] = make_float4(0.f, 0.f, 0.f, 0.f);
    }

#pragma unroll
    for (int h = 0; h < K / KH; ++h) {
        __syncthreads();   // protect LDS from previous half's readers
        // ---- stage W[h*KH .. h*KH+KH) x OUTC into LDS, coalesced float4 ----
        constexpr int NV4 = KH * OUTC / 4;          // float4s per half
        const float4* wsrc = (const float4*)(W + (long)h * KH * OUTC);
        float4* wdst = (float4*)wlds;
#pragma unroll
        for (int p = 0; p < NV4 / 256; ++p) {
            wdst[p * 256 + tid] = wsrc[p * 256 + tid];
        }
        __syncthreads();

        // ---- compute over this half, A ping-pong prefetch ----
        float4 aP[RPT], aQ[RPT];
#pragma unroll
        for (int r = 0; r < RPT; ++r) aP[r] = *(const float4*)(ap[r] + h * KH);
#pragma unroll
        for (int c4 = 0; c4 < KH / 4; ++c4) {
            if (c4 + 1 < KH / 4) {
#pragma unroll
                for (int r = 0; r < RPT; ++r)
                    aQ[r] = *(const float4*)(ap[r] + h * KH + (c4 + 1) * 4);
            }
            float4 w0[4], w1[4];
#pragma unroll
            for (int k = 0; k < 4; ++k) {
                const float* wk = &wlds[(c4 * 4 + k) * OUTC + col0];
                w0[k] = *(const float4*)(wk);
                w1[k] = *(const float4*)(wk + 4);
            }
#pragma unroll
            for (int r = 0; r < RPT; ++r) {
                float av0 = aP[r].x, av1 = aP[r].y, av2 = aP[r].z, av3 = aP[r].w;
                acc[r][0].x = fmaf(av0, w0[0].x, acc[r][0].x);
                acc[r][0].y = fmaf(av0, w0[0].y, acc[r][0].y);
                acc[r][0].z = fmaf(av0, w0[0].z, acc[r][0].z);
                acc[r][0].w = fmaf(av0, w0[0].w, acc[r][0].w);
                acc[r][1].x = fmaf(av0, w1[0].x, acc[r][1].x);
                acc[r][1].y = fmaf(av0, w1[0].y, acc[r][1].y);
                acc[r][1].z = fmaf(av0, w1[0].z, acc[r][1].z);
                acc[r][1].w = fmaf(av0, w1[0].w, acc[r][1].w);
                acc[r][0].x = fmaf(av1, w0[1].x, acc[r][0].x);
                acc[r][0].y = fmaf(av1, w0[1].y, acc[r][0].y);
                acc[r][0].z = fmaf(av1, w0[1].z, acc[r][0].z);
                acc[r][0].w = fmaf(av1, w0[1].w, acc[r][0].w);
                acc[r][1].x = fmaf(av1, w1[1].x, acc[r][1].x);
                acc[r][1].y = fmaf(av1, w1[1].y, acc[r][1].y);
                acc[r][1].z = fmaf(av1, w1[1].z, acc[r][1].z);
                acc[r][1].w = fmaf(av1, w1[1].w, acc[r][1].w);
                acc[r][0].x = fmaf(av2, w0[2].x, acc[r][0].x);
                acc[r][0].y = fmaf(av2, w0[2].y, acc[r][0].y);
                acc[r][0].z = fmaf(av2, w0[2].z, acc[r][0].z);
                acc[r][0].w = fmaf(av2, w0[2].w, acc[r][0].w);
                acc[r][1].x = fmaf(av2, w1[2].x, acc[r][1].x);
                acc[r][1].y = fmaf(av2, w1[2].y, acc[r][1].y);
                acc[r][1].z = fmaf(av2, w1[2].z, acc[r][1].z);
                acc[r][1].w = fmaf(av2, w1[2].w, acc[r][1].w);
                acc[r][0].x = fmaf(av3, w0[3].x, acc[r][0].x);
                acc[r][0].y = fmaf(av3, w0[3].y, acc[r][0].y);
                acc[r][0].z = fmaf(av3, w0[3].z, acc[r][0].z);
                acc[r][0].w = fmaf(av3, w0[3].w, acc[r][0].w);
                acc[r][1].x = fmaf(av3, w1[3].x, acc[r][1].x);
                acc[r][1].y = fmaf(av3, w1[3].y, acc[r][1].y);
                acc[r][1].z = fmaf(av3, w1[3].z, acc[r][1].z);
                acc[r][1].w = fmaf(av3, w1[3].w, acc[r][1].w);
            }
#pragma unroll
            for (int r = 0; r < RPT; ++r) aP[r] = aQ[r];
        }
    }

#pragma unroll
    for (int r = 0; r < RPT; ++r) {
        int rr = row0 + r;
        if (rr < n_rows) {
            float* cp = C + (long)rr * OUTC + col0;
            *(float4*)(cp)     = acc[r][0];
            *(float4*)(cp + 4) = acc[r][1];
        }
    }
}

// ---------------------------------------------------------------------------
// Attention scores: one thread per (node, head); float4 loads of the D-vec.
// ---------------------------------------------------------------------------
template<int D>
__global__ void scores_kernel(const float* __restrict__ h,
                              const float* __restrict__ a_src,
                              const float* __restrict__ a_dst,
                              float* __restrict__ s_src,
                              float* __restrict__ s_dst) {
    int i = blockIdx.x * blockDim.x + threadIdx.x;   // over N_NODES*HEADS
    if (i >= N_NODES * HEADS) return;
    int hd = i & 7;
    const float4* hp = (const float4*)(h + (long)i * D);
    const float4* as = (const float4*)(a_src + hd * D);
    const float4* ad = (const float4*)(a_dst + hd * D);
    float ss = 0.f, sd = 0.f;
#pragma unroll
    for (int r = 0; r < D / 4; ++r) {
        float4 v = hp[r], s4 = as[r], d4 = ad[r];
        ss = fmaf(v.x, s4.x, ss); ss = fmaf(v.y, s4.y, ss);
        ss = fmaf(v.z, s4.z, ss); ss = fmaf(v.w, s4.w, ss);
        sd = fmaf(v.x, d4.x, sd); sd = fmaf(v.y, d4.y, sd);
        sd = fmaf(v.z, d4.z, sd); sd = fmaf(v.w, d4.w, sd);
    }
    s_src[i] = ss;
    s_dst[i] = sd;
}

// ---------------------------------------------------------------------------
// CSR build: count -> block scan -> scan of block sums -> add offsets -> scatter
// ---------------------------------------------------------------------------
__global__ void count_kernel(const int* __restrict__ dst, int* __restrict__ counts) {
    int e = blockIdx.x * blockDim.x + threadIdx.x;
    if (e < N_EDGES) atomicAdd(&counts[dst[e]], 1);
}

__global__ void scan_block_kernel(const int* __restrict__ counts, int* __restrict__ rs,
                                  int* __restrict__ bsums, int n) {
    __shared__ int sh[256];
    int tid = threadIdx.x;
    int base = blockIdx.x * 1024 + tid * 4;
    int c0 = (base + 0 < n) ? counts[base + 0] : 0;
    int c1 = (base + 1 < n) ? counts[base + 1] : 0;
    int c2 = (base + 2 < n) ? counts[base + 2] : 0;
    int c3 = (base + 3 < n) ? counts[base + 3] : 0;
    int p1 = c0, p2 = c0 + c1, p3 = c0 + c1 + c2, tot = c0 + c1 + c2 + c3;
    sh[tid] = tot;
    __syncthreads();
    int run = tot;
    for (int off = 1; off < 256; off <<= 1) {
        int add = (tid >= off) ? sh[tid - off] : 0;
        __syncthreads();
        run += add;
        sh[tid] = run;
        __syncthreads();
    }
    int excl = run - tot;
    if (base + 0 < n) rs[base + 0] = excl;
    if (base + 1 < n) rs[base + 1] = excl + p1;
    if (base + 2 < n) rs[base + 2] = excl + p2;
    if (base + 3 < n) rs[base + 3] = excl + p3;
    if (tid == 255) bsums[blockIdx.x] = run;   // block total
}

__global__ void scan_sums_kernel(int* __restrict__ bsums, int nb) {
    if (blockIdx.x == 0 && threadIdx.x == 0) {
        int run = 0;
        for (int i = 0; i < nb; ++i) { int c = bsums[i]; bsums[i] = run; run += c; }
    }
}

__global__ void add_offsets_kernel(int* __restrict__ rs, const int* __restrict__ bsums,
                                   int* __restrict__ cursor, int n) {
    int tid = threadIdx.x;
    int base = blockIdx.x * 1024 + tid * 4;
    int add = bsums[blockIdx.x];
#pragma unroll
    for (int j = 0; j < 4; ++j) {
        int i = base + j;
        if (i < n) { int v = rs[i] + add; rs[i] = v; cursor[i] = v; }
    }
    if (blockIdx.x == 0 && tid == 0) rs[n] = N_EDGES;
}

__global__ void scatter_kernel(const int* __restrict__ src, const int* __restrict__ dst,
                               int* __restrict__ cursor, int* __restrict__ eidx) {
    int e = blockIdx.x * blockDim.x + threadIdx.x;
    if (e >= N_EDGES) return;
    int d = dst[e];
    int pos = atomicAdd(&cursor[d], 1);
    eidx[pos] = src[e];
}

// ---------------------------------------------------------------------------
// Wave-per-node fused aggregation + softmax + finalize (R7 structure).
// One wave = one dst node; 64 lanes span the feature row; per edge one
// coalesced row load; eidx wave-uniform; 4x unroll keeps 4 gathers in
// flight at ~12 VGPRs of state.
// ---------------------------------------------------------------------------
template<int D, bool RELU>
__global__ __launch_bounds__(256)
void aggregate_wave_kernel(const int* __restrict__ rs, const int* __restrict__ eidx,
                           const float* __restrict__ h,
                           const float* __restrict__ ssrc, const float* __restrict__ sdst,
                           const float* __restrict__ bias, float* __restrict__ out) {
    constexpr int F = HEADS * D;       // 128 or 64
    constexpr int EPL = F / 64;        // elements per lane: 2 or 1
    int lane = threadIdx.x & 63;
    int node = blockIdx.x * (256 / 64) + (threadIdx.x >> 6);
    node = __builtin_amdgcn_readfirstlane(node);
    if (node >= N_NODES) return;
    int hd = lane >> 3;                // head owning this lane's slice

    float sdv = sdst[node * HEADS + hd];
    // self-loop contribution
    float sc0 = ssrc[node * HEADS + hd] + sdv;
    float w0 = __expf(sc0 > 0.f ? sc0 : NEG_SLOPE * sc0);
    float wsum = w0;

    float accx, accy = 0.f;
    if constexpr (EPL == 2) {
        float2 v = *(const float2*)(h + (long)node * F + lane * 2);
        accx = w0 * v.x; accy = w0 * v.y;
    } else {
        accx = w0 * h[(long)node * F + lane];
    }

    int e0 = rs[node], e1 = rs[node + 1];
    int e = e0;

    // ---- unroll-by-4: independent addresses, ~12 VGPRs of in-flight state ----
    for (; e + 4 <= e1; e += 4) {
        int sA = eidx[e + 0];
        int sB = eidx[e + 1];
        int sC = eidx[e + 2];
        int sD = eidx[e + 3];
        float cA = ssrc[sA * HEADS + hd] + sdv;
        float cB = ssrc[sB * HEADS + hd] + sdv;
        float cC = ssrc[sC * HEADS + hd] + sdv;
        float cD = ssrc[sD * HEADS + hd] + sdv;
        float wA = __expf(cA > 0.f ? cA : NEG_SLOPE * cA);
        float wB = __expf(cB > 0.f ? cB : NEG_SLOPE * cB);
        float wC = __expf(cC > 0.f ? cC : NEG_SLOPE * cC);
        float wD = __expf(cD > 0.f ? cD : NEG_SLOPE * cD);
        wsum += (wA + wB) + (wC + wD);
        if constexpr (EPL == 2) {
            float2 vA = *(const float2*)(h + (long)sA * F + lane * 2);
            float2 vB = *(const float2*)(h + (long)sB * F + lane * 2);
            float2 vC = *(const float2*)(h + (long)sC * F + lane * 2);
            float2 vD = *(const float2*)(h + (long)sD * F + lane * 2);
            accx = fmaf(wA, vA.x, accx); accy = fmaf(wA, vA.y, accy);
            accx = fmaf(wB, vB.x, accx); accy = fmaf(wB, vB.y, accy);
            accx = fmaf(wC, vC.x, accx); accy = fmaf(wC, vC.y, accy);
            accx = fmaf(wD, vD.x, accx); accy = fmaf(wD, vD.y, accy);
        } else {
            float vA = h[(long)sA * F + lane];
            float vB = h[(long)sB * F + lane];
            float vC = h[(long)sC * F + lane];
            float vD = h[(long)sD * F + lane];
            accx = fmaf(wA, vA, accx);
            accx = fmaf(wB, vB, accx);
            accx = fmaf(wC, vC, accx);
            accx = fmaf(wD, vD, accx);
        }
    }

    // ---- remainder ----
    for (; e < e1; ++e) {
        int s = eidx[e];
        float sc = ssrc[s * HEADS + hd] + sdv;
        float we = __expf(sc > 0.f ? sc : NEG_SLOPE * sc);
        wsum += we;
        if constexpr (EPL == 2) {
            float2 v = *(const float2*)(h + (long)s * F + lane * 2);
            accx = fmaf(we, v.x, accx); accy = fmaf(we, v.y, accy);
        } else {
            accx = fmaf(we, h[(long)s * F + lane], accx);
        }
    }

    float inv = 1.f / (wsum + 1e-16f);
    if constexpr (EPL == 2) {
        float2 b = *(const float2*)(bias + lane * 2);
        float ox = accx * inv + b.x;
        float oy = accy * inv + b.y;
        if (RELU) { ox = fmaxf(ox, 0.f); oy = fmaxf(oy, 0.f); }
        *(float2*)(out + (long)node * F + lane * 2) = make_float2(ox, oy);
    } else {
        float o = accx * inv + bias[lane];
        if (RELU) o = fmaxf(o, 0.f);
        out[(long)node * F + lane] = o;
    }
}

extern "C" void kernel_launch(void* const* d_in, const int* in_sizes, int n_in,
                              void* d_out, int out_size, void* d_ws, size_t ws_size,
                              hipStream_t stream) {
    const float* x   = (const float*)d_in[0];
    const int*   ei  = (const int*)d_in[1];      // [2, N_EDGES] row-major
    const float* W1  = (const float*)d_in[2];
    const float* a1s = (const float*)d_in[3];
    const float* a1d = (const float*)d_in[4];
    const float* b1  = (const float*)d_in[5];
    const float* W2  = (const float*)d_in[6];
    const float* a2s = (const float*)d_in[7];
    const float* a2d = (const float*)d_in[8];
    const float* b2  = (const float*)d_in[9];
    float* out = (float*)d_out;

    const int* src = ei;
    const int* dst = ei + N_EDGES;

    // ---- workspace layout ----
    float* ws = (float*)d_ws;
    float* bufA = ws;                                  // N*128 : h1, later h2 (N*64)
    float* bufB = bufA + (size_t)N_NODES * 128;        // N*128 : out1
    float* ssrc = bufB + (size_t)N_NODES * 128;        // N*8
    float* sdst = ssrc + (size_t)N_NODES * HEADS;      // N*8
    int* counts    = (int*)(sdst + (size_t)N_NODES * HEADS);  // N
    int* row_start = counts + N_NODES;                 // N+1
    int* cursor    = row_start + N_NODES + 1;          // N
    int* bsums     = cursor + N_NODES;                 // 128
    int* eidx      = bsums + 128;                      // N_EDGES

    const int nb_scan = (N_NODES + 1023) / 1024;       // 98

    // ---- CSR build (shared by both layers) ----
    hipMemsetAsync(counts, 0, (size_t)N_NODES * sizeof(int), stream);
    count_kernel<<<(N_EDGES + 255) / 256, 256, 0, stream>>>(dst, counts);
    scan_block_kernel<<<nb_scan, 256, 0, stream>>>(counts, row_start, bsums, N_NODES);
    scan_sums_kernel<<<1, 64, 0, stream>>>(bsums, nb_scan);
    add_offsets_kernel<<<nb_scan, 256, 0, stream>>>(row_start, bsums, cursor, N_NODES);
    scatter_kernel<<<(N_EDGES + 255) / 256, 256, 0, stream>>>(src, dst, cursor, eidx);

    // ---- Layer 1 ----
    gemm_lds_kernel<128, 128, 4><<<(N_NODES + 63) / 64, 256, 0, stream>>>(x, W1, bufA, N_NODES);
    scores_kernel<D1><<<(N_NODES * HEADS + 255) / 256, 256, 0, stream>>>(bufA, a1s, a1d, ssrc, sdst);
    aggregate_wave_kernel<D1, true><<<(N_NODES + 3) / 4, 256, 0, stream>>>(
        row_start, eidx, bufA, ssrc, sdst, b1, bufB);

    // ---- Layer 2 ----
    gemm_lds_kernel<128, 64, 2><<<(N_NODES + 63) / 64, 256, 0, stream>>>(bufB, W2, bufA, N_NODES);
    scores_kernel<D2><<<(N_NODES * HEADS + 255) / 256, 256, 0, stream>>>(bufA, a2s, a2d, ssrc, sdst);
    aggregate_wave_kernel<D2, false><<<(N_NODES + 3) / 4, 256, 0, stream>>>(
        row_start, eidx, bufA, ssrc, sdst, b2, out);
}

// Round 10
// 693.098 us; speedup vs baseline: 5.8244x; 4.6582x over previous
//
#include <hip/hip_runtime.h>
#include <math.h>

#define N_NODES 100000
#define N_EDGES 1600000
#define IN_DIM 128
#define HEADS 8
#define D1 16
#define D2 8
#define NEG_SLOPE 0.2f

// ---------------------------------------------------------------------------
// Register-tiled GEMM (R5 structure, RPT x 8 tile).
// History: R5 (8x8, unroll 4, launch_bounds(256)) = 144 us, VGPR 84, NO
// spill — the only spill-free tiled variant. Its limit was latency:
// 782 blocks (3/CU), occupancy 21%, VALUBusy 16%.
// R10 change: RPT=4 halves per-thread state (acc 32 regs, in-flight 48) and
// doubles the grid (1563 blocks, ~6 blocks/CU, ~2x resident waves).
// Discipline (R8/R9 lessons): straight-line unrolled code, no lambdas, no
// address-taken arrays, modest unroll(2) — keep VGPR <= 96.
// ---------------------------------------------------------------------------
template<int K, int OUTC, int RPT>
__global__ __launch_bounds__(256)
void gemm_tile_kernel(const float* __restrict__ A, const float* __restrict__ W,
                      float* __restrict__ C, int n_rows) {
    constexpr int CT = OUTC / 8;       // col-threads per row group
    constexpr int RT = 256 / CT;       // row-threads
    constexpr int BM = RT * RPT;       // rows per block
    int tid = threadIdx.x;
    int ct = tid % CT;
    int rt = tid / CT;
    int row0 = blockIdx.x * BM + rt * RPT;
    int col0 = ct * 8;

    const float* ap[RPT];
#pragma unroll
    for (int r = 0; r < RPT; ++r) {
        int rr = row0 + r;
        rr = rr < n_rows ? rr : n_rows - 1;   // clamp: keep address valid
        ap[r] = A + (long)rr * K;
    }

    float4 acc[RPT][2];
#pragma unroll
    for (int r = 0; r < RPT; ++r) {
        acc[r][0] = make_float4(0.f, 0.f, 0.f, 0.f);
        acc[r][1] = make_float4(0.f, 0.f, 0.f, 0.f);
    }

    const float* wp = W + col0;
#pragma unroll 2
    for (int c4 = 0; c4 < K / 4; ++c4) {
        float4 a[RPT];
#pragma unroll
        for (int r = 0; r < RPT; ++r) a[r] = *(const float4*)(ap[r] + c4 * 4);
        float4 w0[4], w1[4];
#pragma unroll
        for (int k = 0; k < 4; ++k) {
            const float* wk = wp + (c4 * 4 + k) * OUTC;
            w0[k] = *(const float4*)(wk);
            w1[k] = *(const float4*)(wk + 4);
        }
#pragma unroll
        for (int r = 0; r < RPT; ++r) {
            float a0 = a[r].x, a1 = a[r].y, a2 = a[r].z, a3 = a[r].w;
            acc[r][0].x = fmaf(a0, w0[0].x, acc[r][0].x);
            acc[r][0].y = fmaf(a0, w0[0].y, acc[r][0].y);
            acc[r][0].z = fmaf(a0, w0[0].z, acc[r][0].z);
            acc[r][0].w = fmaf(a0, w0[0].w, acc[r][0].w);
            acc[r][1].x = fmaf(a0, w1[0].x, acc[r][1].x);
            acc[r][1].y = fmaf(a0, w1[0].y, acc[r][1].y);
            acc[r][1].z = fmaf(a0, w1[0].z, acc[r][1].z);
            acc[r][1].w = fmaf(a0, w1[0].w, acc[r][1].w);
            acc[r][0].x = fmaf(a1, w0[1].x, acc[r][0].x);
            acc[r][0].y = fmaf(a1, w0[1].y, acc[r][0].y);
            acc[r][0].z = fmaf(a1, w0[1].z, acc[r][0].z);
            acc[r][0].w = fmaf(a1, w0[1].w, acc[r][0].w);
            acc[r][1].x = fmaf(a1, w1[1].x, acc[r][1].x);
            acc[r][1].y = fmaf(a1, w1[1].y, acc[r][1].y);
            acc[r][1].z = fmaf(a1, w1[1].z, acc[r][1].z);
            acc[r][1].w = fmaf(a1, w1[1].w, acc[r][1].w);
            acc[r][0].x = fmaf(a2, w0[2].x, acc[r][0].x);
            acc[r][0].y = fmaf(a2, w0[2].y, acc[r][0].y);
            acc[r][0].z = fmaf(a2, w0[2].z, acc[r][0].z);
            acc[r][0].w = fmaf(a2, w0[2].w, acc[r][0].w);
            acc[r][1].x = fmaf(a2, w1[2].x, acc[r][1].x);
            acc[r][1].y = fmaf(a2, w1[2].y, acc[r][1].y);
            acc[r][1].z = fmaf(a2, w1[2].z, acc[r][1].z);
            acc[r][1].w = fmaf(a2, w1[2].w, acc[r][1].w);
            acc[r][0].x = fmaf(a3, w0[3].x, acc[r][0].x);
            acc[r][0].y = fmaf(a3, w0[3].y, acc[r][0].y);
            acc[r][0].z = fmaf(a3, w0[3].z, acc[r][0].z);
            acc[r][0].w = fmaf(a3, w0[3].w, acc[r][0].w);
            acc[r][1].x = fmaf(a3, w1[3].x, acc[r][1].x);
            acc[r][1].y = fmaf(a3, w1[3].y, acc[r][1].y);
            acc[r][1].z = fmaf(a3, w1[3].z, acc[r][1].z);
            acc[r][1].w = fmaf(a3, w1[3].w, acc[r][1].w);
        }
    }

#pragma unroll
    for (int r = 0; r < RPT; ++r) {
        int rr = row0 + r;
        if (rr < n_rows) {
            float* cp = C + (long)rr * OUTC + col0;
            *(float4*)(cp)     = acc[r][0];
            *(float4*)(cp + 4) = acc[r][1];
        }
    }
}

// ---------------------------------------------------------------------------
// Attention scores: one thread per (node, head); float4 loads of the D-vec.
// ---------------------------------------------------------------------------
template<int D>
__global__ void scores_kernel(const float* __restrict__ h,
                              const float* __restrict__ a_src,
                              const float* __restrict__ a_dst,
                              float* __restrict__ s_src,
                              float* __restrict__ s_dst) {
    int i = blockIdx.x * blockDim.x + threadIdx.x;   // over N_NODES*HEADS
    if (i >= N_NODES * HEADS) return;
    int hd = i & 7;
    const float4* hp = (const float4*)(h + (long)i * D);
    const float4* as = (const float4*)(a_src + hd * D);
    const float4* ad = (const float4*)(a_dst + hd * D);
    float ss = 0.f, sd = 0.f;
#pragma unroll
    for (int r = 0; r < D / 4; ++r) {
        float4 v = hp[r], s4 = as[r], d4 = ad[r];
        ss = fmaf(v.x, s4.x, ss); ss = fmaf(v.y, s4.y, ss);
        ss = fmaf(v.z, s4.z, ss); ss = fmaf(v.w, s4.w, ss);
        sd = fmaf(v.x, d4.x, sd); sd = fmaf(v.y, d4.y, sd);
        sd = fmaf(v.z, d4.z, sd); sd = fmaf(v.w, d4.w, sd);
    }
    s_src[i] = ss;
    s_dst[i] = sd;
}

// ---------------------------------------------------------------------------
// CSR build: count -> block scan -> scan of block sums -> add offsets -> scatter
// ---------------------------------------------------------------------------
__global__ void count_kernel(const int* __restrict__ dst, int* __restrict__ counts) {
    int e = blockIdx.x * blockDim.x + threadIdx.x;
    if (e < N_EDGES) atomicAdd(&counts[dst[e]], 1);
}

__global__ void scan_block_kernel(const int* __restrict__ counts, int* __restrict__ rs,
                                  int* __restrict__ bsums, int n) {
    __shared__ int sh[256];
    int tid = threadIdx.x;
    int base = blockIdx.x * 1024 + tid * 4;
    int c0 = (base + 0 < n) ? counts[base + 0] : 0;
    int c1 = (base + 1 < n) ? counts[base + 1] : 0;
    int c2 = (base + 2 < n) ? counts[base + 2] : 0;
    int c3 = (base + 3 < n) ? counts[base + 3] : 0;
    int p1 = c0, p2 = c0 + c1, p3 = c0 + c1 + c2, tot = c0 + c1 + c2 + c3;
    sh[tid] = tot;
    __syncthreads();
    int run = tot;
    for (int off = 1; off < 256; off <<= 1) {
        int add = (tid >= off) ? sh[tid - off] : 0;
        __syncthreads();
        run += add;
        sh[tid] = run;
        __syncthreads();
    }
    int excl = run - tot;
    if (base + 0 < n) rs[base + 0] = excl;
    if (base + 1 < n) rs[base + 1] = excl + p1;
    if (base + 2 < n) rs[base + 2] = excl + p2;
    if (base + 3 < n) rs[base + 3] = excl + p3;
    if (tid == 255) bsums[blockIdx.x] = run;   // block total
}

__global__ void scan_sums_kernel(int* __restrict__ bsums, int nb) {
    if (blockIdx.x == 0 && threadIdx.x == 0) {
        int run = 0;
        for (int i = 0; i < nb; ++i) { int c = bsums[i]; bsums[i] = run; run += c; }
    }
}

__global__ void add_offsets_kernel(int* __restrict__ rs, const int* __restrict__ bsums,
                                   int* __restrict__ cursor, int n) {
    int tid = threadIdx.x;
    int base = blockIdx.x * 1024 + tid * 4;
    int add = bsums[blockIdx.x];
#pragma unroll
    for (int j = 0; j < 4; ++j) {
        int i = base + j;
        if (i < n) { int v = rs[i] + add; rs[i] = v; cursor[i] = v; }
    }
    if (blockIdx.x == 0 && tid == 0) rs[n] = N_EDGES;
}

__global__ void scatter_kernel(const int* __restrict__ src, const int* __restrict__ dst,
                               int* __restrict__ cursor, int* __restrict__ eidx) {
    int e = blockIdx.x * blockDim.x + threadIdx.x;
    if (e >= N_EDGES) return;
    int d = dst[e];
    int pos = atomicAdd(&cursor[d], 1);
    eidx[pos] = src[e];
}

// ---------------------------------------------------------------------------
// Wave-per-node fused aggregation + softmax + finalize (R7 structure).
// One wave = one dst node; 64 lanes span the feature row; per edge one
// coalesced row load; eidx wave-uniform; 4x unroll keeps 4 gathers in
// flight at ~12 VGPRs of state.
// ---------------------------------------------------------------------------
template<int D, bool RELU>
__global__ __launch_bounds__(256)
void aggregate_wave_kernel(const int* __restrict__ rs, const int* __restrict__ eidx,
                           const float* __restrict__ h,
                           const float* __restrict__ ssrc, const float* __restrict__ sdst,
                           const float* __restrict__ bias, float* __restrict__ out) {
    constexpr int F = HEADS * D;       // 128 or 64
    constexpr int EPL = F / 64;        // elements per lane: 2 or 1
    int lane = threadIdx.x & 63;
    int node = blockIdx.x * (256 / 64) + (threadIdx.x >> 6);
    node = __builtin_amdgcn_readfirstlane(node);
    if (node >= N_NODES) return;
    int hd = lane >> 3;                // head owning this lane's slice

    float sdv = sdst[node * HEADS + hd];
    // self-loop contribution
    float sc0 = ssrc[node * HEADS + hd] + sdv;
    float w0 = __expf(sc0 > 0.f ? sc0 : NEG_SLOPE * sc0);
    float wsum = w0;

    float accx, accy = 0.f;
    if constexpr (EPL == 2) {
        float2 v = *(const float2*)(h + (long)node * F + lane * 2);
        accx = w0 * v.x; accy = w0 * v.y;
    } else {
        accx = w0 * h[(long)node * F + lane];
    }

    int e0 = rs[node], e1 = rs[node + 1];
    int e = e0;

    // ---- unroll-by-4: independent addresses, ~12 VGPRs of in-flight state ----
    for (; e + 4 <= e1; e += 4) {
        int sA = eidx[e + 0];
        int sB = eidx[e + 1];
        int sC = eidx[e + 2];
        int sD = eidx[e + 3];
        float cA = ssrc[sA * HEADS + hd] + sdv;
        float cB = ssrc[sB * HEADS + hd] + sdv;
        float cC = ssrc[sC * HEADS + hd] + sdv;
        float cD = ssrc[sD * HEADS + hd] + sdv;
        float wA = __expf(cA > 0.f ? cA : NEG_SLOPE * cA);
        float wB = __expf(cB > 0.f ? cB : NEG_SLOPE * cB);
        float wC = __expf(cC > 0.f ? cC : NEG_SLOPE * cC);
        float wD = __expf(cD > 0.f ? cD : NEG_SLOPE * cD);
        wsum += (wA + wB) + (wC + wD);
        if constexpr (EPL == 2) {
            float2 vA = *(const float2*)(h + (long)sA * F + lane * 2);
            float2 vB = *(const float2*)(h + (long)sB * F + lane * 2);
            float2 vC = *(const float2*)(h + (long)sC * F + lane * 2);
            float2 vD = *(const float2*)(h + (long)sD * F + lane * 2);
            accx = fmaf(wA, vA.x, accx); accy = fmaf(wA, vA.y, accy);
            accx = fmaf(wB, vB.x, accx); accy = fmaf(wB, vB.y, accy);
            accx = fmaf(wC, vC.x, accx); accy = fmaf(wC, vC.y, accy);
            accx = fmaf(wD, vD.x, accx); accy = fmaf(wD, vD.y, accy);
        } else {
            float vA = h[(long)sA * F + lane];
            float vB = h[(long)sB * F + lane];
            float vC = h[(long)sC * F + lane];
            float vD = h[(long)sD * F + lane];
            accx = fmaf(wA, vA, accx);
            accx = fmaf(wB, vB, accx);
            accx = fmaf(wC, vC, accx);
            accx = fmaf(wD, vD, accx);
        }
    }

    // ---- remainder ----
    for (; e < e1; ++e) {
        int s = eidx[e];
        float sc = ssrc[s * HEADS + hd] + sdv;
        float we = __expf(sc > 0.f ? sc : NEG_SLOPE * sc);
        wsum += we;
        if constexpr (EPL == 2) {
            float2 v = *(const float2*)(h + (long)s * F + lane * 2);
            accx = fmaf(we, v.x, accx); accy = fmaf(we, v.y, accy);
        } else {
            accx = fmaf(we, h[(long)s * F + lane], accx);
        }
    }

    float inv = 1.f / (wsum + 1e-16f);
    if constexpr (EPL == 2) {
        float2 b = *(const float2*)(bias + lane * 2);
        float ox = accx * inv + b.x;
        float oy = accy * inv + b.y;
        if (RELU) { ox = fmaxf(ox, 0.f); oy = fmaxf(oy, 0.f); }
        *(float2*)(out + (long)node * F + lane * 2) = make_float2(ox, oy);
    } else {
        float o = accx * inv + bias[lane];
        if (RELU) o = fmaxf(o, 0.f);
        out[(long)node * F + lane] = o;
    }
}

extern "C" void kernel_launch(void* const* d_in, const int* in_sizes, int n_in,
                              void* d_out, int out_size, void* d_ws, size_t ws_size,
                              hipStream_t stream) {
    const float* x   = (const float*)d_in[0];
    const int*   ei  = (const int*)d_in[1];      // [2, N_EDGES] row-major
    const float* W1  = (const float*)d_in[2];
    const float* a1s = (const float*)d_in[3];
    const float* a1d = (const float*)d_in[4];
    const float* b1  = (const float*)d_in[5];
    const float* W2  = (const float*)d_in[6];
    const float* a2s = (const float*)d_in[7];
    const float* a2d = (const float*)d_in[8];
    const float* b2  = (const float*)d_in[9];
    float* out = (float*)d_out;

    const int* src = ei;
    const int* dst = ei + N_EDGES;

    // ---- workspace layout ----
    float* ws = (float*)d_ws;
    float* bufA = ws;                                  // N*128 : h1, later h2 (N*64)
    float* bufB = bufA + (size_t)N_NODES * 128;        // N*128 : out1
    float* ssrc = bufB + (size_t)N_NODES * 128;        // N*8
    float* sdst = ssrc + (size_t)N_NODES * HEADS;      // N*8
    int* counts    = (int*)(sdst + (size_t)N_NODES * HEADS);  // N
    int* row_start = counts + N_NODES;                 // N+1
    int* cursor    = row_start + N_NODES + 1;          // N
    int* bsums     = cursor + N_NODES;                 // 128
    int* eidx      = bsums + 128;                      // N_EDGES

    const int nb_scan = (N_NODES + 1023) / 1024;       // 98

    // ---- CSR build (shared by both layers) ----
    hipMemsetAsync(counts, 0, (size_t)N_NODES * sizeof(int), stream);
    count_kernel<<<(N_EDGES + 255) / 256, 256, 0, stream>>>(dst, counts);
    scan_block_kernel<<<nb_scan, 256, 0, stream>>>(counts, row_start, bsums, N_NODES);
    scan_sums_kernel<<<1, 64, 0, stream>>>(bsums, nb_scan);
    add_offsets_kernel<<<nb_scan, 256, 0, stream>>>(row_start, bsums, cursor, N_NODES);
    scatter_kernel<<<(N_EDGES + 255) / 256, 256, 0, stream>>>(src, dst, cursor, eidx);

    // ---- Layer 1 ----
    gemm_tile_kernel<128, 128, 4><<<(N_NODES + 63) / 64, 256, 0, stream>>>(x, W1, bufA, N_NODES);
    scores_kernel<D1><<<(N_NODES * HEADS + 255) / 256, 256, 0, stream>>>(bufA, a1s, a1d, ssrc, sdst);
    aggregate_wave_kernel<D1, true><<<(N_NODES + 3) / 4, 256, 0, stream>>>(
        row_start, eidx, bufA, ssrc, sdst, b1, bufB);

    // ---- Layer 2 ----
    gemm_tile_kernel<128, 64, 2><<<(N_NODES + 63) / 64, 256, 0, stream>>>(bufB, W2, bufA, N_NODES);
    scores_kernel<D2><<<(N_NODES * HEADS + 255) / 256, 256, 0, stream>>>(bufA, a2s, a2d, ssrc, sdst);
    aggregate_wave_kernel<D2, false><<<(N_NODES + 3) / 4, 256, 0, stream>>>(
        row_start, eidx, bufA, ssrc, sdst, b2, out);
}